// Round 4
// baseline (1649.834 us; speedup 1.0000x reference)
//
#include <hip/hip_runtime.h>

// GRNN scan: B=512 sequences, T=8192 steps. Round 14.
// R13 post-mortem: txn-spreading REGRESSED (424->522 scan) - per-wave txn
// cap falsified. R11-R13 pattern: producer ~= consumer ~= 31-39k cyc/chunk,
// so one-sided fixes can't win; the pipelined producer+barrier structure is
// the local minimum.
// R14: 3-phase restructure. W depends only on A,C,D (data-independent):
//  A1: 1 serial thread, bare 17-fma Riccati, stores 32 chunk-boundary P's
//      (fused into transpose_in kernel as extra block; ~115us issue-bound).
//  K2: 32 blocks replay 256 steps each from boundaries (bit-identical
//      arithmetic), write 256KB W-stream to ws (~5us).
//  K3: pure consumer scan: NO producer, NO barriers, NO LDS. W read from
//      L2-resident stream via wave-uniform loads, 8-set register ring with
//      6-granule lookahead; dy ring on transposed layout (proven R12).
// Removes barrier drain + lgkm WAR + LDS pipe + conflicts in one move.

#define DT_C 1e-3f
#define MAXU 0.1f
#define T_LEN 8192
#define T4 (T_LEN / 2)          // 4096 float4 granules (2 steps each)
#define CHUNK 256               // steps per expansion chunk
#define NCHUNK (T_LEN / CHUNK)  // 32
#define BROWS 512               // batch rows

__device__ __forceinline__ float clipf(float v, float lo, float hi) {
    return fminf(fmaxf(v, lo), hi);
}
#define MEDU(x) __builtin_amdgcn_fmed3f((x), -MAXU, MAXU)

// --- one special-path Riccati step (C=I, D=diag; symmetric P) -------------
// identical arithmetic to the proven producer PSTEP (R9-R13)
#define RSTEP_S()                                                             \
    {                                                                         \
        const float xi00 = p00 + d00;                                         \
        const float xi11 = p11 + d11;                                         \
        const float s2   = p01 * p01;                                         \
        const float q00  = fmaf(xi00, xi00, s2);                              \
        const float q11  = fmaf(xi11, xi11, s2);                              \
        const float q01  = p01 * (xi00 + xi11);                               \
        const float t00  = fmaf(K00, p00, fmaf(A2dt01, p01, cd0));            \
        const float t11  = fmaf(A2dt10, p01, fmaf(K11, p11, cd1));            \
        const float t01  = fmaf(adt10, p00, fmaf(K01, p01, adt01 * p11));     \
        p00 = fmaf(-DT_C, q00, t00);                                          \
        p01 = fmaf(-DT_C, q01, t01);                                          \
        p11 = fmaf(-DT_C, q11, t11);                                          \
    }

// --- one generic-path Riccati step (clips kept; matches mono/producer) ----
#define RSTEP_G()                                                             \
    {                                                                         \
        const float xi00 = p00*c00 + p01*c01 + d00;                           \
        const float xi01 = p00*c10 + p01*c11 + d10;                           \
        const float xi10 = p10*c00 + p11*c01 + d01;                           \
        const float xi11 = p10*c10 + p11*c11 + d11;                           \
        const float g00 = a00*p00 + a01*p10 + p00*a00 + p01*a01 + d00 - (xi00*xi00 + xi01*xi01); \
        const float g01 = a00*p01 + a01*p11 + p00*a10 + p01*a11 + d01 - (xi00*xi10 + xi01*xi11); \
        const float g10 = a10*p00 + a11*p10 + p10*a00 + p11*a01 + d10 - (xi10*xi00 + xi11*xi01); \
        const float g11 = a10*p01 + a11*p11 + p10*a10 + p11*a11 + d11 - (xi10*xi10 + xi11*xi11); \
        p00 = clipf(p00 + g00 * DT_C, -1.f, 1.f);                             \
        p01 = clipf(p01 + g01 * DT_C, -1.f, 1.f);                             \
        p10 = clipf(p10 + g10 * DT_C, -1.f, 1.f);                             \
        p11 = clipf(p11 + g11 * DT_C, -1.f, 1.f);                             \
    }

// ============= K1: input transpose [B][T4]->[T4][B] + fused A1 ============
// grid (T4/32 + 1, BROWS/32); block (gridDim.x-1, 0) runs the serial A1
// boundary pass instead of a transpose tile. With do_tr=0 and grid (1,1)
// only A1 runs (mid path, no transposes).
__global__ __launch_bounds__(256) void transpose_in_a1(
    const float4* __restrict__ src, float4* __restrict__ dst,
    const float* __restrict__ Am, const float* __restrict__ Cm,
    const float* __restrict__ Dm, float4* __restrict__ bnd, int do_tr)
{
    if ((int)blockIdx.x == (int)gridDim.x - 1) {
        if (blockIdx.y != 0 || threadIdx.x != 0) return;
        const float a00 = Am[0], a01 = Am[1], a10 = Am[2], a11 = Am[3];
        const float c00 = Cm[0], c01 = Cm[1], c10 = Cm[2], c11 = Cm[3];
        const float d00 = Dm[0], d01 = Dm[1], d10 = Dm[2], d11 = Dm[3];
        const bool special = (c00 == 1.f) && (c01 == 0.f) && (c10 == 0.f) &&
                             (c11 == 1.f) && (d01 == 0.f) && (d10 == 0.f);
        const float adt00 = a00 * DT_C, adt01 = a01 * DT_C;
        const float adt10 = a10 * DT_C, adt11 = a11 * DT_C;
        (void)adt00; (void)adt11;
        if (special) {
            const float K00 = 1.f + 2.f * adt00, A2dt01 = 2.f * adt01;
            const float K11 = 1.f + 2.f * adt11, A2dt10 = 2.f * adt10;
            const float K01 = 1.f + (a00 + a11) * DT_C;
            const float cd0 = DT_C * d00, cd1 = DT_C * d11;
            float p00 = 1.f, p01 = 0.f, p11 = 1.f;
            for (int c = 0; c < NCHUNK; ++c) {
                bnd[c] = make_float4(p00, p01, p11, 0.f);
                for (int i = 0; i < CHUNK; i += 8) {
                    RSTEP_S() RSTEP_S() RSTEP_S() RSTEP_S()
                    RSTEP_S() RSTEP_S() RSTEP_S() RSTEP_S()
                }
            }
        } else {
            float p00 = 1.f, p01 = 0.f, p10 = 0.f, p11 = 1.f;
            for (int c = 0; c < NCHUNK; ++c) {
                bnd[c] = make_float4(p00, p01, p10, p11);
                for (int i = 0; i < CHUNK; i += 4) {
                    RSTEP_G() RSTEP_G() RSTEP_G() RSTEP_G()
                }
            }
        }
        return;
    }
    if (!do_tr) return;
    __shared__ float4 tile[32][33];
    const int tx = threadIdx.x & 31;
    const int ty = threadIdx.x >> 5;
    const int c0 = blockIdx.x * 32;
    const int r0 = blockIdx.y * 32;
#pragma unroll
    for (int i = 0; i < 32; i += 8)
        tile[ty + i][tx] = src[(size_t)(r0 + ty + i) * T4 + (c0 + tx)];
    __syncthreads();
#pragma unroll
    for (int i = 0; i < 32; i += 8)
        dst[(size_t)(c0 + ty + i) * BROWS + (r0 + tx)] = tile[tx][ty + i];
}

// ============= K2: parallel W expansion, 32 blocks x 256 steps ============
// wst layout: per step t, wst[2t] = Mdt, wst[2t+1] = Xi (same packing the
// proven consumer expects: granule G -> wst[4G .. 4G+3]).
__global__ __launch_bounds__(64) void expand_w(
    const float* __restrict__ Am, const float* __restrict__ Cm,
    const float* __restrict__ Dm, const float4* __restrict__ bnd,
    float4* __restrict__ wst)
{
    if (threadIdx.x != 0) return;
    const int c = blockIdx.x;
    const float a00 = Am[0], a01 = Am[1], a10 = Am[2], a11 = Am[3];
    const float c00 = Cm[0], c01 = Cm[1], c10 = Cm[2], c11 = Cm[3];
    const float d00 = Dm[0], d01 = Dm[1], d10 = Dm[2], d11 = Dm[3];
    const bool special = (c00 == 1.f) && (c01 == 0.f) && (c10 == 0.f) &&
                         (c11 == 1.f) && (d01 == 0.f) && (d10 == 0.f);
    const float adt00 = a00 * DT_C, adt01 = a01 * DT_C;
    const float adt10 = a10 * DT_C, adt11 = a11 * DT_C;
    float4* wout = wst + (size_t)c * (CHUNK * 2);
    const float4 s = bnd[c];
    if (special) {
        const float K00 = 1.f + 2.f * adt00, A2dt01 = 2.f * adt01;
        const float K11 = 1.f + 2.f * adt11, A2dt10 = 2.f * adt10;
        const float K01 = 1.f + (a00 + a11) * DT_C;
        const float cd0 = DT_C * d00, cd1 = DT_C * d11;
        float p00 = s.x, p01 = s.y, p11 = s.z;
#pragma unroll 4
        for (int i = 0; i < CHUNK; ++i) {
            const float xi00 = p00 + d00, xi01 = p01, xi11 = p11 + d11;
            float4 mv, xv;
            mv.x = fmaf(-DT_C, xi00, adt00);   // mdt00
            mv.y = fmaf(-DT_C, xi01, adt10);   // mdt10
            mv.z = fmaf(-DT_C, xi01, adt01);   // mdt01
            mv.w = fmaf(-DT_C, xi11, adt11);   // mdt11
            xv = make_float4(xi00, xi01, xi01, xi11);
            wout[2 * i]     = mv;
            wout[2 * i + 1] = xv;
            RSTEP_S()
        }
    } else {
        float p00 = s.x, p01 = s.y, p10 = s.z, p11 = s.w;
#pragma unroll 4
        for (int i = 0; i < CHUNK; ++i) {
            const float xi00 = p00*c00 + p01*c01 + d00;
            const float xi01 = p00*c10 + p01*c11 + d10;
            const float xi10 = p10*c00 + p11*c01 + d01;
            const float xi11 = p10*c10 + p11*c11 + d11;
            const float m00 = a00 - (xi00*c00 + xi01*c10);
            const float m01 = a01 - (xi00*c01 + xi01*c11);
            const float m10 = a10 - (xi10*c00 + xi11*c10);
            const float m11 = a11 - (xi10*c01 + xi11*c11);
            float4 mv, xv;
            mv.x = m00 * DT_C; mv.y = m10 * DT_C;
            mv.z = m01 * DT_C; mv.w = m11 * DT_C;
            xv = make_float4(xi00, xi10, xi01, xi11);
            wout[2 * i]     = mv;
            wout[2 * i + 1] = xv;
            RSTEP_G()
        }
    }
}

// ============= K3: pure-consumer scan (no LDS, no barriers) ===============
// tr=1: inA/outA are [T4][BROWS] (coalesced); tr=0: [B][T4] (gather).
__global__ __launch_bounds__(64, 1) void grnn_scan(
    const float4* __restrict__ inA, const float4* __restrict__ wst,
    const float* __restrict__ Cm, float4* __restrict__ outA, int tr)
{
    const int lane = threadIdx.x;
    const int b = blockIdx.x * 64 + lane;
    const float cdt00 = Cm[0] * DT_C, cdt01 = Cm[1] * DT_C;
    const float cdt10 = Cm[2] * DT_C, cdt11 = Cm[3] * DT_C;
    float x0 = 1.f, x1 = 0.f;

#define IDX(G) (tr ? ((size_t)(G) * BROWS + b) : ((size_t)b * T4 + (G)))

    // dy ring: 8-granule lookahead (proven R12)
    float4 d0 = inA[IDX(0)], d1 = inA[IDX(1)], d2 = inA[IDX(2)], d3 = inA[IDX(3)];
    float4 d4 = inA[IDX(4)], d5 = inA[IDX(5)], d6 = inA[IDX(6)], d7 = inA[IDX(7)];
    // W ring: 8 sets (granules), consumed-then-reloaded 8 ahead
    float4 s0a, s0b, s0c, s0d, s1a, s1b, s1c, s1d;
    float4 t0a, t0b, t0c, t0d, t1a, t1b, t1c, t1d;
    float4 u0a, u0b, u0c, u0d, u1a, u1b, u1c, u1d;
    float4 v0a, v0b, v0c, v0d, v1a, v1b, v1c, v1d;

#define WLGG(P, G)                                                            \
    {                                                                         \
        const int gg = (G) < T4 ? (G) : (T4 - 1);                             \
        const float4* wp = wst + 4 * (size_t)gg;                              \
        P##a = wp[0]; P##b = wp[1]; P##c = wp[2]; P##d = wp[3];               \
    }

    // one granule = 2 steps. P##a/c = Mdt step0/1, P##b/d = Xi step0/1.
#define GRANC(P, DJ, OG)                                                      \
    {                                                                         \
        const float4 dyv = DJ;                                                \
        {                                                                     \
            const int nog = (OG) + 8;                                         \
            const int rg = nog < T4 ? nog : (T4 - 1);                         \
            DJ = inA[IDX(rg)];                                                \
        }                                                                     \
        float4 ov;                                                            \
        ov.x = fmaf(cdt00, x0, cdt01 * x1);                                   \
        ov.y = fmaf(cdt10, x0, cdt11 * x1);                                   \
        float e0 = fmaf(P##b.x, dyv.x, P##b.z * dyv.y);                       \
        float e1 = fmaf(P##b.y, dyv.x, P##b.w * dyv.y);                       \
        float dx0 = fmaf(P##a.x, x0, fmaf(P##a.z, x1, e0));                   \
        float dx1 = fmaf(P##a.y, x0, fmaf(P##a.w, x1, e1));                   \
        x0 += MEDU(dx0);                                                      \
        x1 += MEDU(dx1);                                                      \
        ov.z = fmaf(cdt00, x0, cdt01 * x1);                                   \
        ov.w = fmaf(cdt10, x0, cdt11 * x1);                                   \
        e0 = fmaf(P##d.x, dyv.z, P##d.z * dyv.w);                             \
        e1 = fmaf(P##d.y, dyv.z, P##d.w * dyv.w);                             \
        dx0 = fmaf(P##c.x, x0, fmaf(P##c.z, x1, e0));                         \
        dx1 = fmaf(P##c.y, x0, fmaf(P##c.w, x1, e1));                         \
        x0 += MEDU(dx0);                                                      \
        x1 += MEDU(dx1);                                                      \
        outA[IDX(OG)] = ov;                                                   \
    }

    WLGG(s0, 0) WLGG(s1, 1) WLGG(t0, 2) WLGG(t1, 3)
    WLGG(u0, 4) WLGG(u1, 5) WLGG(v0, 6) WLGG(v1, 7)
    for (int q = 0; q < T4 / 8; ++q) {
        const int g = 8 * q;
        GRANC(s0, d0, g + 0) GRANC(s1, d1, g + 1) WLGG(s0, g + 8)  WLGG(s1, g + 9)
        GRANC(t0, d2, g + 2) GRANC(t1, d3, g + 3) WLGG(t0, g + 10) WLGG(t1, g + 11)
        GRANC(u0, d4, g + 4) GRANC(u1, d5, g + 5) WLGG(u0, g + 12) WLGG(u1, g + 13)
        GRANC(v0, d6, g + 6) GRANC(v1, d7, g + 7) WLGG(v0, g + 14) WLGG(v1, g + 15)
    }
#undef GRANC
#undef WLGG
#undef IDX
}

// ============= K4: output transpose (generic tiled) =======================
__global__ __launch_bounds__(256) void transpose_f4(
    const float4* __restrict__ src, float4* __restrict__ dst,
    int rows, int cols)
{
    __shared__ float4 tile[32][33];
    const int tx = threadIdx.x & 31;
    const int ty = threadIdx.x >> 5;
    const int c0 = blockIdx.x * 32;
    const int r0 = blockIdx.y * 32;
#pragma unroll
    for (int i = 0; i < 32; i += 8)
        tile[ty + i][tx] = src[(size_t)(r0 + ty + i) * cols + (c0 + tx)];
    __syncthreads();
#pragma unroll
    for (int i = 0; i < 32; i += 8)
        dst[(size_t)(c0 + ty + i) * rows + (r0 + tx)] = tile[tx][ty + i];
}

// ---------------- fallback: verified monolithic kernel --------------------
__global__ __launch_bounds__(64) void grnn_mono(
    const float* __restrict__ inp, const float* __restrict__ Am,
    const float* __restrict__ Cm, const float* __restrict__ Dm,
    float* __restrict__ out, int B)
{
    const int b = blockIdx.x * blockDim.x + threadIdx.x;
    if (b >= B) return;
    const float a00 = Am[0], a01 = Am[1], a10 = Am[2], a11 = Am[3];
    const float c00 = Cm[0], c01 = Cm[1], c10 = Cm[2], c11 = Cm[3];
    const float d00 = Dm[0], d01 = Dm[1], d10 = Dm[2], d11 = Dm[3];
    float x0 = 1.0f, x1 = 0.0f;
    float p00 = 1.0f, p01 = 0.0f, p10 = 0.0f, p11 = 1.0f;
    const float2* __restrict__ in2 = reinterpret_cast<const float2*>(inp) + (size_t)b * T_LEN;
    float2* __restrict__ out2 = reinterpret_cast<float2*>(out) + (size_t)b * T_LEN;
#pragma unroll 4
    for (int t = 0; t < T_LEN; ++t) {
        float2 o;
        o.x = (c00 * x0 + c01 * x1) * DT_C;
        o.y = (c10 * x0 + c11 * x1) * DT_C;
        out2[t] = o;
        const float xi00 = p00 * c00 + p01 * c01 + d00;
        const float xi01 = p00 * c10 + p01 * c11 + d10;
        const float xi10 = p10 * c00 + p11 * c01 + d01;
        const float xi11 = p10 * c10 + p11 * c11 + d11;
        const float m00 = a00 - (xi00 * c00 + xi01 * c10);
        const float m01 = a01 - (xi00 * c01 + xi01 * c11);
        const float m10 = a10 - (xi10 * c00 + xi11 * c10);
        const float m11 = a11 - (xi10 * c01 + xi11 * c11);
        const float2 dy = in2[t];
        float dx0 = (m00 * x0 + m01 * x1) * DT_C + xi00 * dy.x + xi01 * dy.y;
        float dx1 = (m10 * x0 + m11 * x1) * DT_C + xi10 * dy.x + xi11 * dy.y;
        x0 += clipf(dx0, -MAXU, MAXU);
        x1 += clipf(dx1, -MAXU, MAXU);
        const float g00 = a00*p00 + a01*p10 + p00*a00 + p01*a01 + d00 - (xi00*xi00 + xi01*xi01);
        const float g01 = a00*p01 + a01*p11 + p00*a10 + p01*a11 + d01 - (xi00*xi10 + xi01*xi11);
        const float g10 = a10*p00 + a11*p10 + p10*a00 + p11*a01 + d10 - (xi10*xi00 + xi11*xi01);
        const float g11 = a10*p01 + a11*p11 + p10*a10 + p11*a11 + d11 - (xi10*xi10 + xi11*xi11);
        p00 = clipf(p00 + g00 * DT_C, -1.0f, 1.0f);
        p01 = clipf(p01 + g01 * DT_C, -1.0f, 1.0f);
        p10 = clipf(p10 + g10 * DT_C, -1.0f, 1.0f);
        p11 = clipf(p11 + g11 * DT_C, -1.0f, 1.0f);
    }
}

extern "C" void kernel_launch(void* const* d_in, const int* in_sizes, int n_in,
                              void* d_out, int out_size, void* d_ws, size_t ws_size,
                              hipStream_t stream) {
    const float* inp = (const float*)d_in[0];
    const float* Am  = (const float*)d_in[1];
    const float* Cm  = (const float*)d_in[2];
    const float* Dm  = (const float*)d_in[3];
    float* out = (float*)d_out;
    const int B = in_sizes[0] / (T_LEN * 2);  // 512

    // ws layout: [bnd: 32 f4][wstream: 16384 f4] ... @512KB: [inT][outT]
    float4* bnd = (float4*)d_ws;
    float4* wst = bnd + 32;
    float4* inT  = (float4*)d_ws + 32768;               // offset 512 KiB
    float4* outT = inT + (size_t)T4 * BROWS;
    const size_t need_mid  = (size_t)(32 + T_LEN * 2) * sizeof(float4); // ~257KB
    const size_t need_full = (size_t)512 * 1024 +
                             (size_t)2 * T4 * BROWS * sizeof(float4);   // 64.5MB

    if (B == BROWS && d_ws != nullptr && ws_size >= need_full) {
        // K1: transpose input + fused serial boundary pass (extra block)
        hipLaunchKernelGGL(transpose_in_a1, dim3(T4 / 32 + 1, BROWS / 32),
                           dim3(256), 0, stream,
                           reinterpret_cast<const float4*>(inp), inT,
                           Am, Cm, Dm, bnd, 1);
        // K2: parallel W expansion
        hipLaunchKernelGGL(expand_w, dim3(NCHUNK), dim3(64), 0, stream,
                           Am, Cm, Dm, bnd, wst);
        // K3: pure-consumer scan on transposed layout
        hipLaunchKernelGGL(grnn_scan, dim3(BROWS / 64), dim3(64), 0, stream,
                           inT, wst, Cm, outT, 1);
        // K4: transpose output back
        hipLaunchKernelGGL(transpose_f4, dim3(BROWS / 32, T4 / 32), dim3(256),
                           0, stream,
                           outT, reinterpret_cast<float4*>(out), T4, BROWS);
    } else if ((B % 64) == 0 && d_ws != nullptr && ws_size >= need_mid) {
        // mid path: no transposes (gather I/O), same 3-phase W machinery
        hipLaunchKernelGGL(transpose_in_a1, dim3(1, 1), dim3(256), 0, stream,
                           reinterpret_cast<const float4*>(inp), bnd,
                           Am, Cm, Dm, bnd, 0);
        hipLaunchKernelGGL(expand_w, dim3(NCHUNK), dim3(64), 0, stream,
                           Am, Cm, Dm, bnd, wst);
        hipLaunchKernelGGL(grnn_scan, dim3(B / 64), dim3(64), 0, stream,
                           reinterpret_cast<const float4*>(inp), wst, Cm,
                           reinterpret_cast<float4*>(out), 0);
    } else {
        hipLaunchKernelGGL(grnn_mono, dim3((B + 63) / 64), dim3(64), 0, stream,
                           inp, Am, Cm, Dm, out, B);
    }
}

// Round 5
// 760.918 us; speedup vs baseline: 2.1682x; 2.1682x over previous
//
#include <hip/hip_runtime.h>

// GRNN scan: B=512 sequences, T=8192 steps. Round 15.
// R14 post-mortem: 3-phase structure right, K3 collapsed (1263us, 740
// cyc/granule). VGPR_Count=80 proves the compiler SANK the 8-set global
// W-ring loads to point-of-use (ring needs ~180 VGPR) -> serial L2 latency
// per granule; occupancy 8 waves/GPU exposes every stall.
// R15: K3 stages W through wave-private double-buffered LDS via async
// global_load_lds (16B, can't be sunk), one vmcnt(0) per 128-granule chunk,
// NO barriers (single wave owns buffer). W consumed as uniform ds_read_b128
// broadcasts through the 8-set ring + sched_barrier fencing (R12 schedule).
// Layout flag tr -> template (compile-time addressing, saddr-friendly).
// A1 (serial boundary pass, fused in transpose) / K2 (parallel W expand) /
// K4 (output transpose) unchanged from R14.

#define DT_C 1e-3f
#define MAXU 0.1f
#define T_LEN 8192
#define T4 (T_LEN / 2)          // 4096 float4 granules (2 steps each)
#define CHUNK 256               // steps per chunk
#define G_CHUNK (CHUNK / 2)     // 128 granules per chunk
#define NCHUNK (T_LEN / CHUNK)  // 32
#define BROWS 512               // batch rows

__device__ __forceinline__ float clipf(float v, float lo, float hi) {
    return fminf(fmaxf(v, lo), hi);
}
#define MEDU(x) __builtin_amdgcn_fmed3f((x), -MAXU, MAXU)
#define SB() __builtin_amdgcn_sched_barrier(0)

// --- one special-path Riccati step (C=I, D=diag; symmetric P) -------------
#define RSTEP_S()                                                             \
    {                                                                         \
        const float xi00 = p00 + d00;                                         \
        const float xi11 = p11 + d11;                                         \
        const float s2   = p01 * p01;                                         \
        const float q00  = fmaf(xi00, xi00, s2);                              \
        const float q11  = fmaf(xi11, xi11, s2);                              \
        const float q01  = p01 * (xi00 + xi11);                               \
        const float t00  = fmaf(K00, p00, fmaf(A2dt01, p01, cd0));            \
        const float t11  = fmaf(A2dt10, p01, fmaf(K11, p11, cd1));            \
        const float t01  = fmaf(adt10, p00, fmaf(K01, p01, adt01 * p11));     \
        p00 = fmaf(-DT_C, q00, t00);                                          \
        p01 = fmaf(-DT_C, q01, t01);                                          \
        p11 = fmaf(-DT_C, q11, t11);                                          \
    }

// --- one generic-path Riccati step (clips kept) ---------------------------
#define RSTEP_G()                                                             \
    {                                                                         \
        const float xi00 = p00*c00 + p01*c01 + d00;                           \
        const float xi01 = p00*c10 + p01*c11 + d10;                           \
        const float xi10 = p10*c00 + p11*c01 + d01;                           \
        const float xi11 = p10*c10 + p11*c11 + d11;                           \
        const float g00 = a00*p00 + a01*p10 + p00*a00 + p01*a01 + d00 - (xi00*xi00 + xi01*xi01); \
        const float g01 = a00*p01 + a01*p11 + p00*a10 + p01*a11 + d01 - (xi00*xi10 + xi01*xi11); \
        const float g10 = a10*p00 + a11*p10 + p10*a00 + p11*a01 + d10 - (xi10*xi00 + xi11*xi01); \
        const float g11 = a10*p01 + a11*p11 + p10*a10 + p11*a11 + d11 - (xi10*xi10 + xi11*xi11); \
        p00 = clipf(p00 + g00 * DT_C, -1.f, 1.f);                             \
        p01 = clipf(p01 + g01 * DT_C, -1.f, 1.f);                             \
        p10 = clipf(p10 + g10 * DT_C, -1.f, 1.f);                             \
        p11 = clipf(p11 + g11 * DT_C, -1.f, 1.f);                             \
    }

// ============= K1: input transpose [B][T4]->[T4][B] + fused A1 ============
__global__ __launch_bounds__(256) void transpose_in_a1(
    const float4* __restrict__ src, float4* __restrict__ dst,
    const float* __restrict__ Am, const float* __restrict__ Cm,
    const float* __restrict__ Dm, float4* __restrict__ bnd, int do_tr)
{
    if ((int)blockIdx.x == (int)gridDim.x - 1) {
        if (blockIdx.y != 0 || threadIdx.x != 0) return;
        const float a00 = Am[0], a01 = Am[1], a10 = Am[2], a11 = Am[3];
        const float c00 = Cm[0], c01 = Cm[1], c10 = Cm[2], c11 = Cm[3];
        const float d00 = Dm[0], d01 = Dm[1], d10 = Dm[2], d11 = Dm[3];
        const bool special = (c00 == 1.f) && (c01 == 0.f) && (c10 == 0.f) &&
                             (c11 == 1.f) && (d01 == 0.f) && (d10 == 0.f);
        const float adt00 = a00 * DT_C, adt01 = a01 * DT_C;
        const float adt10 = a10 * DT_C, adt11 = a11 * DT_C;
        if (special) {
            const float K00 = 1.f + 2.f * adt00, A2dt01 = 2.f * adt01;
            const float K11 = 1.f + 2.f * adt11, A2dt10 = 2.f * adt10;
            const float K01 = 1.f + (a00 + a11) * DT_C;
            const float cd0 = DT_C * d00, cd1 = DT_C * d11;
            float p00 = 1.f, p01 = 0.f, p11 = 1.f;
            for (int c = 0; c < NCHUNK; ++c) {
                bnd[c] = make_float4(p00, p01, p11, 0.f);
                for (int i = 0; i < CHUNK; i += 8) {
                    RSTEP_S() RSTEP_S() RSTEP_S() RSTEP_S()
                    RSTEP_S() RSTEP_S() RSTEP_S() RSTEP_S()
                }
            }
        } else {
            float p00 = 1.f, p01 = 0.f, p10 = 0.f, p11 = 1.f;
            for (int c = 0; c < NCHUNK; ++c) {
                bnd[c] = make_float4(p00, p01, p10, p11);
                for (int i = 0; i < CHUNK; i += 4) {
                    RSTEP_G() RSTEP_G() RSTEP_G() RSTEP_G()
                }
            }
        }
        return;
    }
    if (!do_tr) return;
    __shared__ float4 tile[32][33];
    const int tx = threadIdx.x & 31;
    const int ty = threadIdx.x >> 5;
    const int c0 = blockIdx.x * 32;
    const int r0 = blockIdx.y * 32;
#pragma unroll
    for (int i = 0; i < 32; i += 8)
        tile[ty + i][tx] = src[(size_t)(r0 + ty + i) * T4 + (c0 + tx)];
    __syncthreads();
#pragma unroll
    for (int i = 0; i < 32; i += 8)
        dst[(size_t)(c0 + ty + i) * BROWS + (r0 + tx)] = tile[tx][ty + i];
}

// ============= K2: parallel W expansion, 32 blocks x 256 steps ============
// wst: per step t, wst[2t] = Mdt, wst[2t+1] = Xi (granule G -> wst[4G..4G+3])
__global__ __launch_bounds__(64) void expand_w(
    const float* __restrict__ Am, const float* __restrict__ Cm,
    const float* __restrict__ Dm, const float4* __restrict__ bnd,
    float4* __restrict__ wst)
{
    if (threadIdx.x != 0) return;
    const int c = blockIdx.x;
    const float a00 = Am[0], a01 = Am[1], a10 = Am[2], a11 = Am[3];
    const float c00 = Cm[0], c01 = Cm[1], c10 = Cm[2], c11 = Cm[3];
    const float d00 = Dm[0], d01 = Dm[1], d10 = Dm[2], d11 = Dm[3];
    const bool special = (c00 == 1.f) && (c01 == 0.f) && (c10 == 0.f) &&
                         (c11 == 1.f) && (d01 == 0.f) && (d10 == 0.f);
    const float adt00 = a00 * DT_C, adt01 = a01 * DT_C;
    const float adt10 = a10 * DT_C, adt11 = a11 * DT_C;
    float4* wout = wst + (size_t)c * (CHUNK * 2);
    const float4 s = bnd[c];
    if (special) {
        const float K00 = 1.f + 2.f * adt00, A2dt01 = 2.f * adt01;
        const float K11 = 1.f + 2.f * adt11, A2dt10 = 2.f * adt10;
        const float K01 = 1.f + (a00 + a11) * DT_C;
        const float cd0 = DT_C * d00, cd1 = DT_C * d11;
        float p00 = s.x, p01 = s.y, p11 = s.z;
#pragma unroll 4
        for (int i = 0; i < CHUNK; ++i) {
            const float xi00 = p00 + d00, xi01 = p01, xi11 = p11 + d11;
            float4 mv, xv;
            mv.x = fmaf(-DT_C, xi00, adt00);
            mv.y = fmaf(-DT_C, xi01, adt10);
            mv.z = fmaf(-DT_C, xi01, adt01);
            mv.w = fmaf(-DT_C, xi11, adt11);
            xv = make_float4(xi00, xi01, xi01, xi11);
            wout[2 * i]     = mv;
            wout[2 * i + 1] = xv;
            RSTEP_S()
        }
    } else {
        float p00 = s.x, p01 = s.y, p10 = s.z, p11 = s.w;
#pragma unroll 4
        for (int i = 0; i < CHUNK; ++i) {
            const float xi00 = p00*c00 + p01*c01 + d00;
            const float xi01 = p00*c10 + p01*c11 + d10;
            const float xi10 = p10*c00 + p11*c01 + d01;
            const float xi11 = p10*c10 + p11*c11 + d11;
            const float m00 = a00 - (xi00*c00 + xi01*c10);
            const float m01 = a01 - (xi00*c01 + xi01*c11);
            const float m10 = a10 - (xi10*c00 + xi11*c10);
            const float m11 = a11 - (xi10*c01 + xi11*c11);
            float4 mv, xv;
            mv.x = m00 * DT_C; mv.y = m10 * DT_C;
            mv.z = m01 * DT_C; mv.w = m11 * DT_C;
            xv = make_float4(xi00, xi10, xi01, xi11);
            wout[2 * i]     = mv;
            wout[2 * i + 1] = xv;
            RSTEP_G()
        }
    }
}

// ============= K3: pure-consumer scan, LDS-staged W (no barriers) =========
// TR=1: inA/outA are [T4][BROWS] (coalesced); TR=0: [B][T4] (gather).
template <int TR>
__global__ __launch_bounds__(64, 1) void grnn_scan(
    const float4* __restrict__ inA, const float4* __restrict__ wst,
    const float* __restrict__ Cm, float4* __restrict__ outA)
{
    __shared__ float4 wlds[2][G_CHUNK * 4];    // 2 x 8KB W double buffer
    const int lane = threadIdx.x;
    const int b = blockIdx.x * 64 + lane;
    const float cdt00 = Cm[0] * DT_C, cdt01 = Cm[1] * DT_C;
    const float cdt10 = Cm[2] * DT_C, cdt11 = Cm[3] * DT_C;
    float x0 = 1.f, x1 = 0.f;

#define IDX(G) (TR ? ((size_t)(G) * BROWS + b) : ((size_t)b * T4 + (G)))

    // async chunk stage: 8 x global_load_lds, 1KB each (64 lanes x 16B).
    // LDS dest = uniform base + lane*16; global src per-lane -> linear copy.
#define STAGE(CH, BUF)                                                        \
    {                                                                         \
        const float4* gs = wst + (size_t)(CH) * (G_CHUNK * 4) + lane;         \
        _Pragma("unroll")                                                     \
        for (int i = 0; i < 8; ++i) {                                         \
            __builtin_amdgcn_global_load_lds(                                 \
                (const __attribute__((address_space(1))) void*)(gs + i * 64), \
                (__attribute__((address_space(3))) void*)&wlds[BUF][i * 64],  \
                16, 0, 0);                                                    \
        }                                                                     \
    }
#define WAITVM()                                                              \
    {                                                                         \
        asm volatile("s_waitcnt vmcnt(0)" ::: "memory");                      \
        __builtin_amdgcn_sched_barrier(0);                                    \
    }

    // dy ring: 8-granule lookahead (proven R12)
    float4 d0 = inA[IDX(0)], d1 = inA[IDX(1)], d2 = inA[IDX(2)], d3 = inA[IDX(3)];
    float4 d4 = inA[IDX(4)], d5 = inA[IDX(5)], d6 = inA[IDX(6)], d7 = inA[IDX(7)];
    // W ring: 8 sets, consumed then reloaded 8 granules ahead (from LDS)
    float4 s0a, s0b, s0c, s0d, s1a, s1b, s1c, s1d;
    float4 t0a, t0b, t0c, t0d, t1a, t1b, t1c, t1d;
    float4 u0a, u0b, u0c, u0d, u1a, u1b, u1c, u1d;
    float4 v0a, v0b, v0c, v0d, v1a, v1b, v1c, v1d;

    // W set load from current chunk's LDS buffer; G is LOCAL granule index,
    // clamped to chunk end (tail loads are never consumed - ring resets).
#define WLG(P, G)                                                             \
    {                                                                         \
        const int gg = (G) < G_CHUNK ? (G) : (G_CHUNK - 1);                   \
        const float4* wp = wbuf + 4 * gg;                                     \
        P##a = wp[0]; P##b = wp[1]; P##c = wp[2]; P##d = wp[3];               \
    }

    // one granule = 2 steps. P##a/c = Mdt step0/1, P##b/d = Xi step0/1.
#define GRANC(P, DJ, OG)                                                      \
    {                                                                         \
        const float4 dyv = DJ;                                                \
        {                                                                     \
            const int nog = (OG) + 8;                                         \
            const int rg = nog < T4 ? nog : (T4 - 1);                         \
            DJ = inA[IDX(rg)];                                                \
        }                                                                     \
        float4 ov;                                                            \
        ov.x = fmaf(cdt00, x0, cdt01 * x1);                                   \
        ov.y = fmaf(cdt10, x0, cdt11 * x1);                                   \
        float e0 = fmaf(P##b.x, dyv.x, P##b.z * dyv.y);                       \
        float e1 = fmaf(P##b.y, dyv.x, P##b.w * dyv.y);                       \
        float dx0 = fmaf(P##a.x, x0, fmaf(P##a.z, x1, e0));                   \
        float dx1 = fmaf(P##a.y, x0, fmaf(P##a.w, x1, e1));                   \
        x0 += MEDU(dx0);                                                      \
        x1 += MEDU(dx1);                                                      \
        ov.z = fmaf(cdt00, x0, cdt01 * x1);                                   \
        ov.w = fmaf(cdt10, x0, cdt11 * x1);                                   \
        e0 = fmaf(P##d.x, dyv.z, P##d.z * dyv.w);                             \
        e1 = fmaf(P##d.y, dyv.z, P##d.w * dyv.w);                             \
        dx0 = fmaf(P##c.x, x0, fmaf(P##c.z, x1, e0));                         \
        dx1 = fmaf(P##c.y, x0, fmaf(P##c.w, x1, e1));                         \
        x0 += MEDU(dx0);                                                      \
        x1 += MEDU(dx1);                                                      \
        outA[IDX(OG)] = ov;                                                   \
    }

    STAGE(0, 0)
    WAITVM()
    for (int c = 0; c < NCHUNK; ++c) {
        if (c + 1 < NCHUNK) {
            if ((c & 1) == 0) STAGE(c + 1, 1) else STAGE(c + 1, 0)
        }
        const float4* wbuf = wlds[c & 1];
        const int ogc = c * G_CHUNK;
        WLG(s0, 0) WLG(s1, 1) WLG(t0, 2) WLG(t1, 3)
        WLG(u0, 4) WLG(u1, 5) WLG(v0, 6) WLG(v1, 7)
        SB();
        for (int q = 0; q < G_CHUNK / 8; ++q) {
            const int g = 8 * q;
            const int og = ogc + g;
            GRANC(s0, d0, og + 0) GRANC(s1, d1, og + 1) SB();
            WLG(s0, g + 8)  WLG(s1, g + 9)  SB();
            GRANC(t0, d2, og + 2) GRANC(t1, d3, og + 3) SB();
            WLG(t0, g + 10) WLG(t1, g + 11) SB();
            GRANC(u0, d4, og + 4) GRANC(u1, d5, og + 5) SB();
            WLG(u0, g + 12) WLG(u1, g + 13) SB();
            GRANC(v0, d6, og + 6) GRANC(v1, d7, og + 7) SB();
            WLG(v0, g + 14) WLG(v1, g + 15) SB();
        }
        WAITVM()   // drain next-chunk stage (+ dy/stores); buffer swap safe
    }
#undef GRANC
#undef WLG
#undef STAGE
#undef WAITVM
#undef IDX
}

// ============= K4: output transpose (generic tiled) =======================
__global__ __launch_bounds__(256) void transpose_f4(
    const float4* __restrict__ src, float4* __restrict__ dst,
    int rows, int cols)
{
    __shared__ float4 tile[32][33];
    const int tx = threadIdx.x & 31;
    const int ty = threadIdx.x >> 5;
    const int c0 = blockIdx.x * 32;
    const int r0 = blockIdx.y * 32;
#pragma unroll
    for (int i = 0; i < 32; i += 8)
        tile[ty + i][tx] = src[(size_t)(r0 + ty + i) * cols + (c0 + tx)];
    __syncthreads();
#pragma unroll
    for (int i = 0; i < 32; i += 8)
        dst[(size_t)(c0 + ty + i) * rows + (r0 + tx)] = tile[tx][ty + i];
}

// ---------------- fallback: verified monolithic kernel --------------------
__global__ __launch_bounds__(64) void grnn_mono(
    const float* __restrict__ inp, const float* __restrict__ Am,
    const float* __restrict__ Cm, const float* __restrict__ Dm,
    float* __restrict__ out, int B)
{
    const int b = blockIdx.x * blockDim.x + threadIdx.x;
    if (b >= B) return;
    const float a00 = Am[0], a01 = Am[1], a10 = Am[2], a11 = Am[3];
    const float c00 = Cm[0], c01 = Cm[1], c10 = Cm[2], c11 = Cm[3];
    const float d00 = Dm[0], d01 = Dm[1], d10 = Dm[2], d11 = Dm[3];
    float x0 = 1.0f, x1 = 0.0f;
    float p00 = 1.0f, p01 = 0.0f, p10 = 0.0f, p11 = 1.0f;
    const float2* __restrict__ in2 = reinterpret_cast<const float2*>(inp) + (size_t)b * T_LEN;
    float2* __restrict__ out2 = reinterpret_cast<float2*>(out) + (size_t)b * T_LEN;
#pragma unroll 4
    for (int t = 0; t < T_LEN; ++t) {
        float2 o;
        o.x = (c00 * x0 + c01 * x1) * DT_C;
        o.y = (c10 * x0 + c11 * x1) * DT_C;
        out2[t] = o;
        const float xi00 = p00 * c00 + p01 * c01 + d00;
        const float xi01 = p00 * c10 + p01 * c11 + d10;
        const float xi10 = p10 * c00 + p11 * c01 + d01;
        const float xi11 = p10 * c10 + p11 * c11 + d11;
        const float m00 = a00 - (xi00 * c00 + xi01 * c10);
        const float m01 = a01 - (xi00 * c01 + xi01 * c11);
        const float m10 = a10 - (xi10 * c00 + xi11 * c10);
        const float m11 = a11 - (xi10 * c01 + xi11 * c11);
        const float2 dy = in2[t];
        float dx0 = (m00 * x0 + m01 * x1) * DT_C + xi00 * dy.x + xi01 * dy.y;
        float dx1 = (m10 * x0 + m11 * x1) * DT_C + xi10 * dy.x + xi11 * dy.y;
        x0 += clipf(dx0, -MAXU, MAXU);
        x1 += clipf(dx1, -MAXU, MAXU);
        const float g00 = a00*p00 + a01*p10 + p00*a00 + p01*a01 + d00 - (xi00*xi00 + xi01*xi01);
        const float g01 = a00*p01 + a01*p11 + p00*a10 + p01*a11 + d01 - (xi00*xi10 + xi01*xi11);
        const float g10 = a10*p00 + a11*p10 + p10*a00 + p11*a01 + d10 - (xi10*xi00 + xi11*xi01);
        const float g11 = a10*p01 + a11*p11 + p10*a10 + p11*a11 + d11 - (xi10*xi10 + xi11*xi11);
        p00 = clipf(p00 + g00 * DT_C, -1.0f, 1.0f);
        p01 = clipf(p01 + g01 * DT_C, -1.0f, 1.0f);
        p10 = clipf(p10 + g10 * DT_C, -1.0f, 1.0f);
        p11 = clipf(p11 + g11 * DT_C, -1.0f, 1.0f);
    }
}

extern "C" void kernel_launch(void* const* d_in, const int* in_sizes, int n_in,
                              void* d_out, int out_size, void* d_ws, size_t ws_size,
                              hipStream_t stream) {
    const float* inp = (const float*)d_in[0];
    const float* Am  = (const float*)d_in[1];
    const float* Cm  = (const float*)d_in[2];
    const float* Dm  = (const float*)d_in[3];
    float* out = (float*)d_out;
    const int B = in_sizes[0] / (T_LEN * 2);  // 512

    // ws layout: [bnd: 32 f4][wstream: 16384 f4] ... @512KB: [inT][outT]
    float4* bnd = (float4*)d_ws;
    float4* wst = bnd + 32;
    float4* inT  = (float4*)d_ws + 32768;               // offset 512 KiB
    float4* outT = inT + (size_t)T4 * BROWS;
    const size_t need_mid  = (size_t)(32 + T_LEN * 2) * sizeof(float4); // ~257KB
    const size_t need_full = (size_t)512 * 1024 +
                             (size_t)2 * T4 * BROWS * sizeof(float4);   // 64.5MB

    if (B == BROWS && d_ws != nullptr && ws_size >= need_full) {
        hipLaunchKernelGGL(transpose_in_a1, dim3(T4 / 32 + 1, BROWS / 32),
                           dim3(256), 0, stream,
                           reinterpret_cast<const float4*>(inp), inT,
                           Am, Cm, Dm, bnd, 1);
        hipLaunchKernelGGL(expand_w, dim3(NCHUNK), dim3(64), 0, stream,
                           Am, Cm, Dm, bnd, wst);
        hipLaunchKernelGGL(HIP_KERNEL_NAME(grnn_scan<1>), dim3(BROWS / 64),
                           dim3(64), 0, stream, inT, wst, Cm, outT);
        hipLaunchKernelGGL(transpose_f4, dim3(BROWS / 32, T4 / 32), dim3(256),
                           0, stream,
                           outT, reinterpret_cast<float4*>(out), T4, BROWS);
    } else if ((B % 64) == 0 && d_ws != nullptr && ws_size >= need_mid) {
        hipLaunchKernelGGL(transpose_in_a1, dim3(1, 1), dim3(256), 0, stream,
                           reinterpret_cast<const float4*>(inp), bnd,
                           Am, Cm, Dm, bnd, 0);
        hipLaunchKernelGGL(expand_w, dim3(NCHUNK), dim3(64), 0, stream,
                           Am, Cm, Dm, bnd, wst);
        hipLaunchKernelGGL(HIP_KERNEL_NAME(grnn_scan<0>), dim3(B / 64),
                           dim3(64), 0, stream,
                           reinterpret_cast<const float4*>(inp), wst, Cm,
                           reinterpret_cast<float4*>(out));
    } else {
        hipLaunchKernelGGL(grnn_mono, dim3((B + 63) / 64), dim3(64), 0, stream,
                           inp, Am, Cm, Dm, out, B);
    }
}

// Round 6
// 514.017 us; speedup vs baseline: 3.2097x; 1.4803x over previous
//
#include <hip/hip_runtime.h>

// GRNN scan: B=512 sequences, T=8192 steps. Round 16.
// R15 post-mortem: scan 1263->364us (LDS staging beat the load-sink), BUT
// total 761: the serial A1 Riccati chain (~350us, ~105 cyc/step) is now
// SEQUENTIAL on the stream - sum of poles instead of max. K3 still 213
// cyc/granule (8-set ring needs ~170 VGPR, got 124 -> ds latency exposed).
// R16: fuse W production back into the scan kernel as a 2nd wave per block
// (intra-block barrier pipeline, no global W, no K2):
//  producer phase(i): lane0 walks 256 steps in XI-SPACE (state=P+D, 11
//    VALU/step, 2-deep diag chain) storing 8-step sub-boundaries to LDS;
//  phase(ii): 32 lanes expand 8 steps each -> W pairs into LDS dbuf;
//  consumer: R15 GRANC with 4-set W ring (fits VGPR budget, prefetch 2
//    granules ~200cyc > ds latency).
// Total = max(producer ~10k, consumer ~16k cyc/chunk), consumer-bound.

#define DT_C 1e-3f
#define MAXU 0.1f
#define T_LEN 8192
#define T4 (T_LEN / 2)          // 4096 float4 granules (2 steps each)
#define CHUNK 256               // steps per chunk
#define G_CHUNK (CHUNK / 2)     // 128 granules per chunk
#define NCHUNK (T_LEN / CHUNK)  // 32
#define BROWS 512               // batch rows

__device__ __forceinline__ float clipf(float v, float lo, float hi) {
    return fminf(fmaxf(v, lo), hi);
}
#define MEDU(x) __builtin_amdgcn_fmed3f((x), -MAXU, MAXU)
#define SB() __builtin_amdgcn_sched_barrier(0)

// ---------------- tiled float4 transpose: src[rows][cols] -> dst[cols][rows]
__global__ __launch_bounds__(256) void transpose_f4(
    const float4* __restrict__ src, float4* __restrict__ dst,
    int rows, int cols)
{
    __shared__ float4 tile[32][33];
    const int tx = threadIdx.x & 31;
    const int ty = threadIdx.x >> 5;
    const int c0 = blockIdx.x * 32;
    const int r0 = blockIdx.y * 32;
#pragma unroll
    for (int i = 0; i < 32; i += 8)
        tile[ty + i][tx] = src[(size_t)(r0 + ty + i) * cols + (c0 + tx)];
    __syncthreads();
#pragma unroll
    for (int i = 0; i < 32; i += 8)
        dst[(size_t)(c0 + ty + i) * rows + (r0 + tx)] = tile[tx][ty + i];
}

// ============= fused scan: wave0 consumer, wave1 W-producer ===============
// inT/outT are [T4][BROWS] float4 (transposed layout, proven R12).
__global__ __launch_bounds__(128, 1) void grnn_fused2(
    const float4* __restrict__ inT, const float* __restrict__ Am,
    const float* __restrict__ Cm, const float* __restrict__ Dm,
    float4* __restrict__ outT)
{
    __shared__ float4 wlds[2][CHUNK * 2];   // 16 KB W double buffer
    __shared__ float4 sbnd[CHUNK / 8];      // 32 sub-boundaries (every 8 steps)
    const int tid = threadIdx.x;
    const int wv = tid >> 6;

    if (wv == 1) {
        // ===================== producer wave =============================
        const int lane = tid & 63;
        const float a00 = Am[0], a01 = Am[1], a10 = Am[2], a11 = Am[3];
        const float c00 = Cm[0], c01 = Cm[1], c10 = Cm[2], c11 = Cm[3];
        const float d00 = Dm[0], d01 = Dm[1], d10 = Dm[2], d11 = Dm[3];
        const bool special = (c00 == 1.f) && (c01 == 0.f) && (c10 == 0.f) &&
                             (c11 == 1.f) && (d01 == 0.f) && (d10 == 0.f);
        const float adt00 = a00 * DT_C, adt01 = a01 * DT_C;
        const float adt10 = a10 * DT_C, adt11 = a11 * DT_C;

        if (special) {
            // xi-space: state u=xi00=p00+d00, w=p01, v=xi11=p11+d11.
            // u' = u*(K00 - dt*u) + A2dt01*w - dt*w^2 + C0u   (2-deep cycle)
            // w' = w*(K01 - dt*(u+v)) + adt10*u + adt01*v + C1w
            // Verified algebraically == RSTEP_S (R9-R15 arithmetic).
            const float K00 = 1.f + 2.f * adt00, A2dt01 = 2.f * adt01;
            const float K11 = 1.f + 2.f * adt11, A2dt10 = 2.f * adt10;
            const float K01 = 1.f + (a00 + a11) * DT_C;
            const float C0u = DT_C * d00 * (1.f - 2.f * a00);
            const float C0v = DT_C * d11 * (1.f - 2.f * a11);
            const float C1w = -(adt10 * d00 + adt01 * d11);

#define XSTEP()                                                               \
            {                                                                 \
                const float w2 = w * w;                                       \
                const float gu = fmaf(-DT_C, u, K00);                         \
                const float gv = fmaf(-DT_C, v, K11);                         \
                const float s  = u + v;                                       \
                const float ru = fmaf(A2dt01, w, fmaf(-DT_C, w2, C0u));       \
                const float rv = fmaf(A2dt10, w, fmaf(-DT_C, w2, C0v));       \
                const float gw = fmaf(-DT_C, s, K01);                         \
                const float rw = fmaf(adt10, u, fmaf(adt01, v, C1w));         \
                const float un = fmaf(u, gu, ru);                             \
                const float vn = fmaf(v, gv, rv);                             \
                const float wn = fmaf(w, gw, rw);                             \
                u = un; v = vn; w = wn;                                       \
            }

            float u = 1.f + d00, w = 0.f, v = 1.f + d11;  // P0=I
            for (int it = 0; it <= NCHUNK; ++it) {
                if (it < NCHUNK) {
                    // phase (i): serial 256 steps, sub-boundary every 8
                    if (lane == 0) {
                        for (int j = 0; j < CHUNK / 8; ++j) {
                            sbnd[j] = make_float4(u, w, v, 0.f);
                            XSTEP() XSTEP() XSTEP() XSTEP()
                            XSTEP() XSTEP() XSTEP() XSTEP()
                        }
                    }
                    asm volatile("s_waitcnt lgkmcnt(0)" ::: "memory");
                    SB();
                    __builtin_amdgcn_wave_barrier();
                    // phase (ii): 32 lanes x 8 steps -> W into LDS dbuf
                    if (lane < CHUNK / 8) {
                        const float4 sb = sbnd[lane];
                        float u2 = sb.x, w2v = sb.y, v2 = sb.z;
                        float4* wdst = wlds[it & 1] + 2 * (lane * 8);
#pragma unroll
                        for (int k = 0; k < 8; ++k) {
                            float4 mv, xv;
                            mv.x = fmaf(-DT_C, u2, adt00);
                            mv.y = fmaf(-DT_C, w2v, adt10);
                            mv.z = fmaf(-DT_C, w2v, adt01);
                            mv.w = fmaf(-DT_C, v2, adt11);
                            xv = make_float4(u2, w2v, w2v, v2);
                            wdst[2 * k]     = mv;
                            wdst[2 * k + 1] = xv;
                            {
                                float u = u2, w = w2v, v = v2;
                                XSTEP()
                                u2 = u; w2v = w; v2 = v;
                            }
                        }
                    }
                }
                __syncthreads();
            }
#undef XSTEP
        } else {
            // generic path: full P, clips kept (mirrors R14 expand_w)
#define RSTEP_G()                                                             \
            {                                                                 \
                const float xi00 = p00*c00 + p01*c01 + d00;                   \
                const float xi01 = p00*c10 + p01*c11 + d10;                   \
                const float xi10 = p10*c00 + p11*c01 + d01;                   \
                const float xi11 = p10*c10 + p11*c11 + d11;                   \
                const float g00 = a00*p00 + a01*p10 + p00*a00 + p01*a01 + d00 - (xi00*xi00 + xi01*xi01); \
                const float g01 = a00*p01 + a01*p11 + p00*a10 + p01*a11 + d01 - (xi00*xi10 + xi01*xi11); \
                const float g10 = a10*p00 + a11*p10 + p10*a00 + p11*a01 + d10 - (xi10*xi00 + xi11*xi01); \
                const float g11 = a10*p01 + a11*p11 + p10*a10 + p11*a11 + d11 - (xi10*xi10 + xi11*xi11); \
                p00 = clipf(p00 + g00 * DT_C, -1.f, 1.f);                     \
                p01 = clipf(p01 + g01 * DT_C, -1.f, 1.f);                     \
                p10 = clipf(p10 + g10 * DT_C, -1.f, 1.f);                     \
                p11 = clipf(p11 + g11 * DT_C, -1.f, 1.f);                     \
            }
            float p00 = 1.f, p01 = 0.f, p10 = 0.f, p11 = 1.f;
            for (int it = 0; it <= NCHUNK; ++it) {
                if (it < NCHUNK) {
                    if (lane == 0) {
                        for (int j = 0; j < CHUNK / 8; ++j) {
                            sbnd[j] = make_float4(p00, p01, p10, p11);
                            RSTEP_G() RSTEP_G() RSTEP_G() RSTEP_G()
                            RSTEP_G() RSTEP_G() RSTEP_G() RSTEP_G()
                        }
                    }
                    asm volatile("s_waitcnt lgkmcnt(0)" ::: "memory");
                    SB();
                    __builtin_amdgcn_wave_barrier();
                    if (lane < CHUNK / 8) {
                        const float4 sb = sbnd[lane];
                        float p00 = sb.x, p01 = sb.y, p10 = sb.z, p11 = sb.w;
                        float4* wdst = wlds[it & 1] + 2 * (lane * 8);
#pragma unroll
                        for (int k = 0; k < 8; ++k) {
                            const float xi00 = p00*c00 + p01*c01 + d00;
                            const float xi01 = p00*c10 + p01*c11 + d10;
                            const float xi10 = p10*c00 + p11*c01 + d01;
                            const float xi11 = p10*c10 + p11*c11 + d11;
                            const float m00 = a00 - (xi00*c00 + xi01*c10);
                            const float m01 = a01 - (xi00*c01 + xi01*c11);
                            const float m10 = a10 - (xi10*c00 + xi11*c10);
                            const float m11 = a11 - (xi10*c01 + xi11*c11);
                            float4 mv, xv;
                            mv.x = m00 * DT_C; mv.y = m10 * DT_C;
                            mv.z = m01 * DT_C; mv.w = m11 * DT_C;
                            xv = make_float4(xi00, xi10, xi01, xi11);
                            wdst[2 * k]     = mv;
                            wdst[2 * k + 1] = xv;
                            RSTEP_G()
                        }
                    }
                }
                __syncthreads();
            }
#undef RSTEP_G
        }
    } else {
        // ===================== consumer wave =============================
        const int lane = tid;
        const int b = blockIdx.x * 64 + lane;
        const float cdt00 = Cm[0] * DT_C, cdt01 = Cm[1] * DT_C;
        const float cdt10 = Cm[2] * DT_C, cdt11 = Cm[3] * DT_C;
        float x0 = 1.f, x1 = 0.f;

#define IDX(G) ((size_t)(G) * BROWS + b)

        // dy ring: 8-granule lookahead (proven R12/R15)
        float4 d0 = inT[IDX(0)], d1 = inT[IDX(1)], d2 = inT[IDX(2)], d3 = inT[IDX(3)];
        float4 d4 = inT[IDX(4)], d5 = inT[IDX(5)], d6 = inT[IDX(6)], d7 = inT[IDX(7)];
        // W ring: 4 sets (fits VGPR budget; prefetch distance 2 granules)
        float4 s0a, s0b, s0c, s0d, s1a, s1b, s1c, s1d;
        float4 t0a, t0b, t0c, t0d, t1a, t1b, t1c, t1d;

#define WLG(P, G)                                                             \
        {                                                                     \
            const int gg = (G) < G_CHUNK ? (G) : (G_CHUNK - 1);               \
            const float4* wp = wbuf + 4 * gg;                                 \
            P##a = wp[0]; P##b = wp[1]; P##c = wp[2]; P##d = wp[3];           \
        }

        // one granule = 2 steps. P##a/c = Mdt step0/1, P##b/d = Xi step0/1.
#define GRANC(P, DJ, OG)                                                      \
        {                                                                     \
            const float4 dyv = DJ;                                            \
            {                                                                 \
                const int nog = (OG) + 8;                                     \
                const int rg = nog < T4 ? nog : (T4 - 1);                     \
                DJ = inT[IDX(rg)];                                            \
            }                                                                 \
            float4 ov;                                                        \
            ov.x = fmaf(cdt00, x0, cdt01 * x1);                               \
            ov.y = fmaf(cdt10, x0, cdt11 * x1);                               \
            float e0 = fmaf(P##b.x, dyv.x, P##b.z * dyv.y);                   \
            float e1 = fmaf(P##b.y, dyv.x, P##b.w * dyv.y);                   \
            float dx0 = fmaf(P##a.x, x0, fmaf(P##a.z, x1, e0));               \
            float dx1 = fmaf(P##a.y, x0, fmaf(P##a.w, x1, e1));               \
            x0 += MEDU(dx0);                                                  \
            x1 += MEDU(dx1);                                                  \
            ov.z = fmaf(cdt00, x0, cdt01 * x1);                               \
            ov.w = fmaf(cdt10, x0, cdt11 * x1);                               \
            e0 = fmaf(P##d.x, dyv.z, P##d.z * dyv.w);                         \
            e1 = fmaf(P##d.y, dyv.z, P##d.w * dyv.w);                         \
            dx0 = fmaf(P##c.x, x0, fmaf(P##c.z, x1, e0));                     \
            dx1 = fmaf(P##c.y, x0, fmaf(P##c.w, x1, e1));                     \
            x0 += MEDU(dx0);                                                  \
            x1 += MEDU(dx1);                                                  \
            outT[IDX(OG)] = ov;                                               \
        }

        for (int it = 0; it <= NCHUNK; ++it) {
            if (it > 0) {
                const int cc = it - 1;
                const float4* wbuf = wlds[cc & 1];
                const int ogc = cc * G_CHUNK;
                WLG(s0, 0) WLG(s1, 1) WLG(t0, 2) WLG(t1, 3)
                SB();
                for (int q = 0; q < G_CHUNK / 8; ++q) {
                    const int g = 8 * q;
                    const int og = ogc + g;
                    GRANC(s0, d0, og + 0) GRANC(s1, d1, og + 1) SB();
                    WLG(s0, g + 4) WLG(s1, g + 5) SB();
                    GRANC(t0, d2, og + 2) GRANC(t1, d3, og + 3) SB();
                    WLG(t0, g + 6) WLG(t1, g + 7) SB();
                    GRANC(s0, d4, og + 4) GRANC(s1, d5, og + 5) SB();
                    WLG(s0, g + 8) WLG(s1, g + 9) SB();
                    GRANC(t0, d6, og + 6) GRANC(t1, d7, og + 7) SB();
                    WLG(t0, g + 10) WLG(t1, g + 11) SB();
                }
            }
            __syncthreads();
        }
#undef GRANC
#undef WLG
#undef IDX
    }
}

// ---------------- fallback: verified monolithic kernel --------------------
__global__ __launch_bounds__(64) void grnn_mono(
    const float* __restrict__ inp, const float* __restrict__ Am,
    const float* __restrict__ Cm, const float* __restrict__ Dm,
    float* __restrict__ out, int B)
{
    const int b = blockIdx.x * blockDim.x + threadIdx.x;
    if (b >= B) return;
    const float a00 = Am[0], a01 = Am[1], a10 = Am[2], a11 = Am[3];
    const float c00 = Cm[0], c01 = Cm[1], c10 = Cm[2], c11 = Cm[3];
    const float d00 = Dm[0], d01 = Dm[1], d10 = Dm[2], d11 = Dm[3];
    float x0 = 1.0f, x1 = 0.0f;
    float p00 = 1.0f, p01 = 0.0f, p10 = 0.0f, p11 = 1.0f;
    const float2* __restrict__ in2 = reinterpret_cast<const float2*>(inp) + (size_t)b * T_LEN;
    float2* __restrict__ out2 = reinterpret_cast<float2*>(out) + (size_t)b * T_LEN;
#pragma unroll 4
    for (int t = 0; t < T_LEN; ++t) {
        float2 o;
        o.x = (c00 * x0 + c01 * x1) * DT_C;
        o.y = (c10 * x0 + c11 * x1) * DT_C;
        out2[t] = o;
        const float xi00 = p00 * c00 + p01 * c01 + d00;
        const float xi01 = p00 * c10 + p01 * c11 + d10;
        const float xi10 = p10 * c00 + p11 * c01 + d01;
        const float xi11 = p10 * c10 + p11 * c11 + d11;
        const float m00 = a00 - (xi00 * c00 + xi01 * c10);
        const float m01 = a01 - (xi00 * c01 + xi01 * c11);
        const float m10 = a10 - (xi10 * c00 + xi11 * c10);
        const float m11 = a11 - (xi10 * c01 + xi11 * c11);
        const float2 dy = in2[t];
        float dx0 = (m00 * x0 + m01 * x1) * DT_C + xi00 * dy.x + xi01 * dy.y;
        float dx1 = (m10 * x0 + m11 * x1) * DT_C + xi10 * dy.x + xi11 * dy.y;
        x0 += clipf(dx0, -MAXU, MAXU);
        x1 += clipf(dx1, -MAXU, MAXU);
        const float g00 = a00*p00 + a01*p10 + p00*a00 + p01*a01 + d00 - (xi00*xi00 + xi01*xi01);
        const float g01 = a00*p01 + a01*p11 + p00*a10 + p01*a11 + d01 - (xi00*xi10 + xi01*xi11);
        const float g10 = a10*p00 + a11*p10 + p10*a00 + p11*a01 + d10 - (xi10*xi00 + xi11*xi01);
        const float g11 = a10*p01 + a11*p11 + p10*a10 + p11*a11 + d11 - (xi10*xi10 + xi11*xi11);
        p00 = clipf(p00 + g00 * DT_C, -1.0f, 1.0f);
        p01 = clipf(p01 + g01 * DT_C, -1.0f, 1.0f);
        p10 = clipf(p10 + g10 * DT_C, -1.0f, 1.0f);
        p11 = clipf(p11 + g11 * DT_C, -1.0f, 1.0f);
    }
}

extern "C" void kernel_launch(void* const* d_in, const int* in_sizes, int n_in,
                              void* d_out, int out_size, void* d_ws, size_t ws_size,
                              hipStream_t stream) {
    const float* inp = (const float*)d_in[0];
    const float* Am  = (const float*)d_in[1];
    const float* Cm  = (const float*)d_in[2];
    const float* Dm  = (const float*)d_in[3];
    float* out = (float*)d_out;
    const int B = in_sizes[0] / (T_LEN * 2);  // 512

    float4* inT  = (float4*)d_ws;                       // [T4][BROWS]
    float4* outT = inT + (size_t)T4 * BROWS;
    const size_t need_ws = (size_t)2 * T4 * BROWS * sizeof(float4);  // 64 MiB

    if (B == BROWS && d_ws != nullptr && ws_size >= need_ws) {
        // 1) transpose input [B][T4] -> [T4][B]
        hipLaunchKernelGGL(transpose_f4, dim3(T4 / 32, BROWS / 32), dim3(256),
                           0, stream,
                           reinterpret_cast<const float4*>(inp), inT,
                           BROWS, T4);
        // 2) fused producer/consumer scan on transposed layout
        hipLaunchKernelGGL(grnn_fused2, dim3(BROWS / 64), dim3(128), 0,
                           stream, inT, Am, Cm, Dm, outT);
        // 3) transpose output [T4][B] -> [B][T4]
        hipLaunchKernelGGL(transpose_f4, dim3(BROWS / 32, T4 / 32), dim3(256),
                           0, stream,
                           outT, reinterpret_cast<float4*>(out), T4, BROWS);
    } else {
        hipLaunchKernelGGL(grnn_mono, dim3((B + 63) / 64), dim3(64), 0, stream,
                           inp, Am, Cm, Dm, out, B);
    }
}